// Round 10
// baseline (95.706 us; speedup 1.0000x reference)
//
#include <hip/hip_runtime.h>

// WaveletFilterNet fused: haar_forward -> per-channel filter -> haar_inverse
// x: (16,1,2048,2048) fp32, filt: (1,3,1024,1024) fp32, out: (16,1,2048,2048) fp32
//
// Per 2x2 input block {A,B,C,D}:
//   P=A+B+C+D, Q=A-B-C+D (HH), R=A+B-C-D (HL), S=A-B+C-D (LH)
// filt ch0 scales HH, ch1 scales HL, ch2 scales LH (reference returns LL,HH,HL,LH).
//   out[2i  ,2j]=.25(P+q+r+s)  out[2i  ,2j+1]=.25(P-q+r-s)
//   out[2i+1,2j]=.25(P+q-r-s)  out[2i+1,2j+1]=.25(P-q-r+s)
//
// R9 = R8 (95.5us) + nontemporal LOADS on the x stream (read-once). Keeps
// x out of L2/L3 so the filter (12.6MB, reused 16x) stays cache-resident.
// Filter loads cached; stores NT. All x/out accesses 64 lanes x 16B packed.

#define B_    16
#define H_    2048
#define W_    2048
#define H2_   1024
#define W2_   1024

typedef float f32x4 __attribute__((ext_vector_type(4)));
typedef float f32x2 __attribute__((ext_vector_type(2)));

struct Quad { float o00, o01, o10, o11; };

__device__ __forceinline__ Quad haar_block(float A, float Bv, float C, float D,
                                           float f0, float f1, float f2)
{
    const float P = A + Bv + C + D;
    const float q = f0 * (A - Bv - C + D);   // HH
    const float r = f1 * (A + Bv - C - D);   // HL
    const float s = f2 * (A - Bv + C - D);   // LH
    Quad o;
    o.o00 = 0.25f * (P + q + r + s);
    o.o01 = 0.25f * (P - q + r - s);
    o.o10 = 0.25f * (P + q - r - s);
    o.o11 = 0.25f * (P - q - r + s);
    return o;
}

__global__ __launch_bounds__(256) void wavelet_fused_kernel(
    const float* __restrict__ x,
    const float* __restrict__ filt,
    float* __restrict__ out)
{
    // grid = 32768; bid = (spatial_chunk << 4) | batch. Each WG covers half a
    // row-pair: 256 threads x 1 float4 = 1024 input cols.
    const unsigned bid = blockIdx.x;
    const unsigned b   = bid & 15u;
    const unsigned sp  = bid >> 4;            // [0, 2048)
    const unsigned i   = sp >> 1;             // block-row in [0,1024)
    const unsigned jh  = sp & 1u;             // which half-row

    const unsigned jt = jh * 256u + threadIdx.x;   // float4 index in row, [0,512)

    const long long inOff = (((long long)b * H_) + 2 * i) * W_ + (long long)jt * 4;

    const f32x4 t0 = __builtin_nontemporal_load(reinterpret_cast<const f32x4*>(x + inOff));
    const f32x4 c0 = __builtin_nontemporal_load(reinterpret_cast<const f32x4*>(x + inOff + W_));

    const long long fOff = (long long)i * W2_ + (long long)jt * 2;
    const f32x2 f0 = *reinterpret_cast<const f32x2*>(filt + 0 * (H2_ * W2_) + fOff); // HH
    const f32x2 f1 = *reinterpret_cast<const f32x2*>(filt + 1 * (H2_ * W2_) + fOff); // HL
    const f32x2 f2 = *reinterpret_cast<const f32x2*>(filt + 2 * (H2_ * W2_) + fOff); // LH

    const Quad q0 = haar_block(t0.x, t0.y, c0.x, c0.y, f0.x, f1.x, f2.x);
    const Quad q1 = haar_block(t0.z, t0.w, c0.z, c0.w, f0.y, f1.y, f2.y);

    f32x4 o0, o1;
    o0.x = q0.o00; o0.y = q0.o01; o0.z = q1.o00; o0.w = q1.o01;
    o1.x = q0.o10; o1.y = q0.o11; o1.z = q1.o10; o1.w = q1.o11;

    __builtin_nontemporal_store(o0, reinterpret_cast<f32x4*>(out + inOff));
    __builtin_nontemporal_store(o1, reinterpret_cast<f32x4*>(out + inOff + W_));
}

extern "C" void kernel_launch(void* const* d_in, const int* in_sizes, int n_in,
                              void* d_out, int out_size, void* d_ws, size_t ws_size,
                              hipStream_t stream) {
    const float* x    = (const float*)d_in[0];
    const float* filt = (const float*)d_in[1];
    float* out        = (float*)d_out;

    const unsigned total_threads = B_ * H2_ * (W_ / 4); // 16*1024*512 = 8,388,608
    const unsigned block = 256;
    const unsigned grid = total_threads / block;        // 32768
    wavelet_fused_kernel<<<grid, block, 0, stream>>>(x, filt, out);
}